// Round 9
// baseline (365.912 us; speedup 1.0000x reference)
//
#include <hip/hip_runtime.h>
#include <math.h>

#define NB 8192
#define H 1024
#define HH 512
#define NEXP 16
#define NT128 96            // max sum of per-expert ceil(cnt/128), padded
#define AMBIG_THR 1e-3f     // ~50 sigma of split-bf16 logit error

// MFMA 16x16x32 bf16 fragments
typedef __attribute__((ext_vector_type(8))) short bfrag;
typedef __attribute__((ext_vector_type(4))) float f4;

__device__ __forceinline__ f4 MF(bfrag a, bfrag b, f4 c) {
    return __builtin_amdgcn_mfma_f32_16x16x32_bf16(a, b, c, 0, 0, 0);
}
__device__ __forceinline__ unsigned short f2bf(float f) {  // RNE fp32->bf16
    unsigned u = __float_as_uint(f);
    u += 0x7fff + ((u >> 16) & 1);
    return (unsigned short)(u >> 16);
}
__device__ __forceinline__ float bf2f(unsigned short h) {
    return __uint_as_float((unsigned)h << 16);
}

// async global->LDS, 16B per lane; LDS dest is wave-uniform base + lane*16
typedef __attribute__((address_space(1))) const unsigned GAS;
typedef __attribute__((address_space(3))) unsigned LAS;
__device__ __forceinline__ void gld16(const void* g, void* l) {
    __builtin_amdgcn_global_load_lds((GAS*)g, (LAS*)l, 16, 0, 0);
}

// fused split-conversion: q (8192 blocks), w1 (512); block 0 zeroes counters,
// blocks 0..127 zero logitsf (8192x16 f32 = 32768 float4 = 128 blocks x 256).
__global__ __launch_bounds__(256) void cvtA_kernel(
    const float* __restrict__ q, const float* __restrict__ w1,
    unsigned short* __restrict__ qhi, unsigned short* __restrict__ qlo,
    unsigned short* __restrict__ w1hi, unsigned short* __restrict__ w1lo,
    float* __restrict__ logitsf, int* __restrict__ counts, int* __restrict__ ambig_cnt)
{
    const int b = blockIdx.x, t = threadIdx.x;
    if (b == 0) {
        if (t < NEXP) counts[t] = 0;
        if (t == NEXP) ambig_cnt[0] = 0;
    }
    if (b < 128) {                          // BUGFIX (was 512): 128*256 float4 = 8192*16 floats exactly
        float4 z = {0.f, 0.f, 0.f, 0.f};
        ((float4*)logitsf)[b * 256 + t] = z;
    }
    const float* src; unsigned short *hi, *lo; int i;
    if (b < 8192) { src = q;  hi = qhi;  lo = qlo;  i = b * 256 + t; }
    else          { src = w1; hi = w1hi; lo = w1lo; i = (b - 8192) * 256 + t; }
    float4 v = ((const float4*)src)[i];
    ushort4 h, l;
    h.x = f2bf(v.x); l.x = f2bf(v.x - bf2f(h.x));
    h.y = f2bf(v.y); l.y = f2bf(v.y - bf2f(h.y));
    h.z = f2bf(v.z); l.z = f2bf(v.z - bf2f(h.z));
    h.w = f2bf(v.w); l.w = f2bf(v.w - bf2f(h.w));
    ((ushort4*)hi)[i] = h;
    ((ushort4*)lo)[i] = l;
}

// fused plain conversion: exp_w1 (8192 blocks), exp_w2 (8192 blocks)
__global__ __launch_bounds__(256) void cvtB_kernel(
    const float* __restrict__ ew1, const float* __restrict__ ew2,
    unsigned short* __restrict__ d1, unsigned short* __restrict__ d2)
{
    const int b = blockIdx.x, t = threadIdx.x;
    const float* src; unsigned short* dst; int i;
    if (b < 8192) { src = ew1; dst = d1; i = b * 256 + t; }
    else          { src = ew2; dst = d2; i = (b - 8192) * 256 + t; }
    float4 v = ((const float4*)src)[i];
    ushort4 h;
    h.x = f2bf(v.x); h.y = f2bf(v.y); h.z = f2bf(v.z); h.w = f2bf(v.w);
    ((ushort4*)dst)[i] = h;
}

// ---- gating GEMM1 + fused logit contraction ----
// x1 = relu(q @ w1^T + b1) kept in REGISTERS only; per-block partial logits
// sum_c x1[r][c]*w3[m][c] accumulated into logitsf[8192][16] via atomicAdd.
// No x1 materialization (removes 16MB scattered stores + logits GEMM kernel).
// 128x128 tile, 8 waves, 3-buf 96KB + 8KB w3 slice, counted vmcnt(4). grid (64,4).
__global__ __launch_bounds__(512) void g1_kernel(
    const unsigned short* __restrict__ qhi, const unsigned short* __restrict__ qlo,
    const unsigned short* __restrict__ w1hi, const unsigned short* __restrict__ w1lo,
    const float* __restrict__ b1, const float* __restrict__ w3f,
    float* __restrict__ logitsf)
{
    __shared__ unsigned short Ah[3][128][32];
    __shared__ unsigned short Al[3][128][32];
    __shared__ unsigned short Bh[3][128][32];
    __shared__ unsigned short Bl[3][128][32];
    __shared__ float w3s[NEXP][128];

    const int t = threadIdx.x, w = t >> 6, lane = t & 63;
    const int quad = lane >> 4, l16 = lane & 15;
    const int wr = w & 3, wc = w >> 2;          // 4 row-groups x 2 col-groups
    const int rowA0 = blockIdx.x * 128;
    const int colB0 = blockIdx.y * 128;
    const int rl = lane >> 2, sl = lane & 3;    // staging: 16 rows x 4 slots per 1KB chunk

    // stage this block's w3 column slice (16 x 128 fp32) once
    for (int i = t; i < NEXP * 128; i += 512) {
        int m = i >> 7, c = i & 127;
        w3s[m][c] = w3f[(size_t)m * HH + colB0 + c];
    }
    asm volatile("s_waitcnt lgkmcnt(0)" ::: "memory");

    // 32 chunks/kt, 4 per wave: c 0-7 Ah, 8-15 Al, 16-23 Bh, 24-31 Bl (16 rows each)
    const unsigned short* gsrc[4];
    unsigned short* lbase[4];
    #pragma unroll
    for (int j = 0; j < 4; ++j) {
        int c = w + j * 8;
        int rloc; const unsigned short* s; unsigned short* d;
        if (c < 8)       { rloc = c * 16 + rl;        s = qhi  + (size_t)(rowA0 + rloc) * H; d = &Ah[0][c * 16][0]; }
        else if (c < 16) { rloc = (c - 8) * 16 + rl;  s = qlo  + (size_t)(rowA0 + rloc) * H; d = &Al[0][(c - 8) * 16][0]; }
        else if (c < 24) { rloc = (c - 16) * 16 + rl; s = w1hi + (size_t)(colB0 + rloc) * H; d = &Bh[0][(c - 16) * 16][0]; }
        else             { rloc = (c - 24) * 16 + rl; s = w1lo + (size_t)(colB0 + rloc) * H; d = &Bl[0][(c - 24) * 16][0]; }
        int f = (rloc & 3) ^ ((rloc >> 2) & 3);
        gsrc[j]  = s + (sl ^ f) * 8;   // pre-swizzled k-slot in the source
        lbase[j] = d;
    }
    const int bstr = 128 * 32;

    const f4 z4 = {0.f, 0.f, 0.f, 0.f};
    f4 acc[2][4] = {{z4, z4, z4, z4}, {z4, z4, z4, z4}};
    const int sw = (quad ^ (l16 & 3) ^ (l16 >> 2)) * 8;
    const int ra0 = wr * 32 + l16, ra1 = ra0 + 16;
    const int cbase = wc * 64;

    auto STAGE = [&](int buf, int kt) {
        #pragma unroll
        for (int j = 0; j < 4; ++j)
            gld16(gsrc[j] + kt * 32, lbase[j] + buf * bstr);
    };
    auto COMPUTE = [&](int buf) {
        bfrag ah0 = *(const bfrag*)&Ah[buf][ra0][sw];
        bfrag al0 = *(const bfrag*)&Al[buf][ra0][sw];
        bfrag ah1 = *(const bfrag*)&Ah[buf][ra1][sw];
        bfrag al1 = *(const bfrag*)&Al[buf][ra1][sw];
        #pragma unroll
        for (int cb = 0; cb < 4; ++cb) {
            bfrag bh = *(const bfrag*)&Bh[buf][cbase + cb * 16 + l16][sw];
            bfrag bl = *(const bfrag*)&Bl[buf][cbase + cb * 16 + l16][sw];
            acc[0][cb] = MF(al0, bh, MF(ah0, bl, MF(ah0, bh, acc[0][cb])));
            acc[1][cb] = MF(al1, bh, MF(ah1, bl, MF(ah1, bh, acc[1][cb])));
        }
    };

    STAGE(0, 0);
    STAGE(1, 1);
    for (int kt = 0; kt < 32; ++kt) {
        if (kt < 31) asm volatile("s_waitcnt vmcnt(4)" ::: "memory");
        else         asm volatile("s_waitcnt vmcnt(0)" ::: "memory");
        __builtin_amdgcn_s_barrier();
        if (kt < 30) STAGE((kt + 2) % 3, kt + 2);
        COMPUTE(kt % 3);
    }

    // epilogue: v = relu(acc + bias) in registers, then logit partials
    float vv[2][4][4];
    #pragma unroll
    for (int cb = 0; cb < 4; ++cb) {
        float bias = b1[colB0 + cbase + cb * 16 + l16];
        #pragma unroll
        for (int rb = 0; rb < 2; ++rb)
            #pragma unroll
            for (int i = 0; i < 4; ++i)
                vv[rb][cb][i] = fmaxf(acc[rb][cb][i] + bias, 0.f);
    }
    const int rowbase = rowA0 + wr * 32;
    #pragma unroll
    for (int m = 0; m < NEXP; ++m) {
        float w3v[4];
        #pragma unroll
        for (int cb = 0; cb < 4; ++cb) w3v[cb] = w3s[m][cbase + cb * 16 + l16];
        #pragma unroll
        for (int rb = 0; rb < 2; ++rb)
            #pragma unroll
            for (int i = 0; i < 4; ++i) {
                float s = vv[rb][0][i] * w3v[0] + vv[rb][1][i] * w3v[1]
                        + vv[rb][2][i] * w3v[2] + vv[rb][3][i] * w3v[3];
                // reduce across the 16 lanes of this quad (different cols, same rows)
                s += __shfl_xor(s, 1);
                s += __shfl_xor(s, 2);
                s += __shfl_xor(s, 4);
                s += __shfl_xor(s, 8);
                if (l16 == 0)
                    atomicAdd(&logitsf[(size_t)(rowbase + rb * 16 + quad * 4 + i) * NEXP + m], s);
            }
    }
}

// ---- argmax + gate + counts + ambiguity from accumulated fp32 logits ----
__global__ __launch_bounds__(256) void argmax_kernel(
    const float* __restrict__ logitsf, const float* __restrict__ b3,
    int* __restrict__ top1, float* __restrict__ gval, int* __restrict__ counts,
    int* __restrict__ ambig_rows, int* __restrict__ ambig_cnt)
{
    __shared__ int hist[NEXP];
    const int t = threadIdx.x;
    if (t < NEXP) hist[t] = 0;
    __syncthreads();
    const int row = blockIdx.x * 256 + t;
    float lg[NEXP];
    #pragma unroll
    for (int m = 0; m < NEXP; ++m) lg[m] = logitsf[(size_t)row * NEXP + m] + b3[m];
    float best = lg[0], second = -3.4e38f; int bi = 0;
    #pragma unroll
    for (int m = 1; m < NEXP; ++m) {
        float v = lg[m];
        if (v > best) { second = best; best = v; bi = m; }
        else if (v > second) second = v;
    }
    float se = 0.f;
    #pragma unroll
    for (int m = 0; m < NEXP; ++m) se += expf(lg[m] - best);
    top1[row] = bi;
    gval[row] = 1.f / se;
    atomicAdd(&hist[bi], 1);
    if (best - second < AMBIG_THR) {
        int pos = atomicAdd(ambig_cnt, 1);
        if (pos < NB) ambig_rows[pos] = row;
    }
    __syncthreads();
    if (t < NEXP) atomicAdd(&counts[t], hist[t]);
}

// ---- exact fp32 x1 recompute for ambiguous rows, column-parallel ----
__global__ __launch_bounds__(256) void fixup1_kernel(
    const float* __restrict__ q, const float* __restrict__ w1, const float* __restrict__ b1,
    const int* __restrict__ ambig_rows, const int* __restrict__ ambig_cnt,
    float* __restrict__ x1buf)
{
    __shared__ __align__(16) float qrow[H];
    const int t = threadIdx.x, wv = t >> 6, ln = t & 63;
    const int chunk = blockIdx.x & 7;
    const int slot  = blockIdx.x >> 3;
    const int base  = chunk * 64;
    int nn = *ambig_cnt; if (nn > NB) nn = NB;
    for (int ii = slot; ii < nn; ii += 32) {
        int row = ambig_rows[ii];
        ((float4*)qrow)[t] = ((const float4*)(q + (size_t)row * H))[t];
        __syncthreads();
        for (int c = base + wv * 2; c < base + 64; c += 8) {
            const float4* w0 = (const float4*)(w1 + (size_t)c * H);
            const float4* w1r = (const float4*)(w1 + (size_t)(c + 1) * H);
            const float4* qv = (const float4*)qrow;
            float s0 = 0.f, s1 = 0.f;
            #pragma unroll
            for (int j = 0; j < 4; ++j) {
                float4 a = qv[j * 64 + ln];
                float4 b0 = w0[j * 64 + ln];
                float4 b1v = w1r[j * 64 + ln];
                s0 += a.x * b0.x + a.y * b0.y + a.z * b0.z + a.w * b0.w;
                s1 += a.x * b1v.x + a.y * b1v.y + a.z * b1v.z + a.w * b1v.w;
            }
            #pragma unroll
            for (int off = 32; off; off >>= 1) {
                s0 += __shfl_xor(s0, off, 64);
                s1 += __shfl_xor(s1, off, 64);
            }
            if (ln == 0) {
                x1buf[(size_t)ii * HH + c]     = fmaxf(s0 + b1[c], 0.f);
                x1buf[(size_t)ii * HH + c + 1] = fmaxf(s1 + b1[c + 1], 0.f);
            }
        }
        __syncthreads();
    }
}

// ---- logits from exact x1 + top1/gval/counts update ----
__global__ __launch_bounds__(256) void fixup2_kernel(
    const float* __restrict__ x1buf,
    const float* __restrict__ w3, const float* __restrict__ b3,
    const int* __restrict__ ambig_rows, const int* __restrict__ ambig_cnt,
    int* __restrict__ top1, float* __restrict__ gval, int* __restrict__ counts)
{
    __shared__ float lgs[NEXP];
    const int t = threadIdx.x, wv = t >> 6, ln = t & 63;
    int nn = *ambig_cnt; if (nn > NB) nn = NB;
    for (int ii = blockIdx.x; ii < nn; ii += gridDim.x) {
        int row = ambig_rows[ii];
        const float4* xv = (const float4*)(x1buf + (size_t)ii * HH);
        for (int m = wv; m < NEXP; m += 4) {
            const float4* wr = (const float4*)(w3 + (size_t)m * HH);
            float s = 0.f;
            #pragma unroll
            for (int j = 0; j < 2; ++j) {
                float4 a = xv[j * 64 + ln];
                float4 b = wr[j * 64 + ln];
                s += a.x * b.x + a.y * b.y + a.z * b.z + a.w * b.w;
            }
            #pragma unroll
            for (int off = 32; off; off >>= 1) s += __shfl_xor(s, off, 64);
            if (ln == 0) lgs[m] = s + b3[m];
        }
        __syncthreads();
        if (t == 0) {
            float best = lgs[0]; int bi = 0;
            #pragma unroll
            for (int m = 1; m < NEXP; ++m) if (lgs[m] > best) { best = lgs[m]; bi = m; }
            float se = 0.f;
            #pragma unroll
            for (int m = 0; m < NEXP; ++m) se += expf(lgs[m] - best);
            int old = top1[row];
            if (bi != old) {
                atomicSub(&counts[old], 1);
                atomicAdd(&counts[bi], 1);
                top1[row] = bi;
            }
            gval[row] = 1.f / se;
        }
        __syncthreads();
    }
}

// fused offsets + tile-map + scatter (single block; LDS atomics)
__global__ __launch_bounds__(256) void osc_kernel(
    const int* __restrict__ counts,
    int* __restrict__ tm_e, int* __restrict__ tm_p, int* __restrict__ tm_end,
    const int* __restrict__ top1, int* __restrict__ brows)
{
    __shared__ int sbpos[NEXP];
    const int t = threadIdx.x;
    if (t == 0) {
        int run = 0, tile = 0;
        for (int e = 0; e < NEXP; ++e) {
            sbpos[e] = run;
            int beg = run, end = run + counts[e];
            for (int p = beg; p < end; p += 128) {
                tm_e[tile] = e; tm_p[tile] = p; tm_end[tile] = end; ++tile;
            }
            run = end;
        }
        for (; tile < NT128; ++tile) tm_e[tile] = -1;
    }
    __syncthreads();
    for (int i = t; i < NB; i += 256) {
        int e = top1[i];
        int pos = atomicAdd(&sbpos[e], 1);
        brows[pos] = i;
    }
}

// ---- expert GEMM1: h[pos][512] = relu(q[brows[pos]] @ w1[e]^T + b1[e]) ----
// 128x128 tile, 8 waves, 3-buf 48KB, counted vmcnt(2). grid (NT128, 4).
__global__ __launch_bounds__(512) void exp1_kernel(
    const unsigned short* __restrict__ qb, const unsigned short* __restrict__ ew1b,
    const float* __restrict__ eb1,
    const int* __restrict__ tm_e, const int* __restrict__ tm_p, const int* __restrict__ tm_end,
    const int* __restrict__ brows, unsigned short* __restrict__ h)
{
    const int e = tm_e[blockIdx.x];
    if (e < 0) return;                       // block-uniform: safe with barriers
    const int p0 = tm_p[blockIdx.x], end = tm_end[blockIdx.x];

    __shared__ unsigned short A[3][128][32];
    __shared__ unsigned short B[3][128][32];

    const int t = threadIdx.x, w = t >> 6, lane = t & 63;
    const int quad = lane >> 4, l16 = lane & 15;
    const int wr = w & 3, wc = w >> 2;
    const int c0 = blockIdx.y * 128;
    const unsigned short* w1p = ew1b + (size_t)e * HH * H;
    const int rl = lane >> 2, sl = lane & 3;

    const unsigned short* gsrc[2];
    unsigned short* lbase[2];
    #pragma unroll
    for (int j = 0; j < 2; ++j) {
        int c = w + j * 8;
        int rloc; const unsigned short* s; unsigned short* d;
        if (c < 8) {
            rloc = c * 16 + rl;
            int pa = p0 + rloc; if (pa >= end) pa = end - 1;   // ragged tail: duplicate last row
            s = qb + (size_t)brows[pa] * H;
            d = &A[0][c * 16][0];
        } else {
            rloc = (c - 8) * 16 + rl;
            s = w1p + (size_t)(c0 + rloc) * H;
            d = &B[0][(c - 8) * 16][0];
        }
        int f = (rloc & 3) ^ ((rloc >> 2) & 3);
        gsrc[j]  = s + (sl ^ f) * 8;
        lbase[j] = d;
    }
    const int bstr = 128 * 32;

    const f4 z4 = {0.f, 0.f, 0.f, 0.f};
    f4 acc[2][4] = {{z4, z4, z4, z4}, {z4, z4, z4, z4}};
    const int sw = (quad ^ (l16 & 3) ^ (l16 >> 2)) * 8;
    const int ra0 = wr * 32 + l16, ra1 = ra0 + 16;
    const int cbase = wc * 64;

    auto STAGE = [&](int buf, int kt) {
        #pragma unroll
        for (int j = 0; j < 2; ++j)
            gld16(gsrc[j] + kt * 32, lbase[j] + buf * bstr);
    };
    auto COMPUTE = [&](int buf) {
        bfrag a0 = *(const bfrag*)&A[buf][ra0][sw];
        bfrag a1 = *(const bfrag*)&A[buf][ra1][sw];
        #pragma unroll
        for (int cb = 0; cb < 4; ++cb) {
            bfrag bb = *(const bfrag*)&B[buf][cbase + cb * 16 + l16][sw];
            acc[0][cb] = MF(a0, bb, acc[0][cb]);
            acc[1][cb] = MF(a1, bb, acc[1][cb]);
        }
    };

    STAGE(0, 0);
    STAGE(1, 1);
    for (int kt = 0; kt < 32; ++kt) {
        if (kt < 31) asm volatile("s_waitcnt vmcnt(2)" ::: "memory");
        else         asm volatile("s_waitcnt vmcnt(0)" ::: "memory");
        __builtin_amdgcn_s_barrier();
        if (kt < 30) STAGE((kt + 2) % 3, kt + 2);
        COMPUTE(kt % 3);
    }

    const int prow0 = p0 + wr * 32;
    #pragma unroll
    for (int cb = 0; cb < 4; ++cb) {
        int col = c0 + cbase + cb * 16 + l16;
        float bias = eb1[e * HH + col];
        #pragma unroll
        for (int rb = 0; rb < 2; ++rb)
            #pragma unroll
            for (int i = 0; i < 4; ++i) {
                int row = rb * 16 + quad * 4 + i;
                if (prow0 + row < end)
                    h[(size_t)(prow0 + row) * HH + col] = f2bf(fmaxf(acc[rb][cb][i] + bias, 0.f));
            }
    }
}

// ---- expert GEMM2: v = h @ w2[e]^T + b2[e]; psum[row][slot] = partial sum v^2 ----
// 128x128 tile, 8 waves, 3-buf 48KB, counted vmcnt(2). grid (NT128, 8).
__global__ __launch_bounds__(512) void exp2_kernel(
    const unsigned short* __restrict__ h, const unsigned short* __restrict__ ew2b,
    const float* __restrict__ eb2,
    const int* __restrict__ tm_e, const int* __restrict__ tm_p, const int* __restrict__ tm_end,
    const int* __restrict__ brows,
    float* __restrict__ vout, float* __restrict__ psum)
{
    const int e = tm_e[blockIdx.x];
    if (e < 0) return;
    const int p0 = tm_p[blockIdx.x], end = tm_end[blockIdx.x];

    __shared__ unsigned short A[3][128][32];
    __shared__ unsigned short B[3][128][32];

    const int t = threadIdx.x, w = t >> 6, lane = t & 63;
    const int quad = lane >> 4, l16 = lane & 15;
    const int wr = w & 3, wc = w >> 2;
    const int c0 = blockIdx.y * 128;
    const unsigned short* w2p = ew2b + (size_t)e * H * HH;
    const int rl = lane >> 2, sl = lane & 3;

    const unsigned short* gsrc[2];
    unsigned short* lbase[2];
    #pragma unroll
    for (int j = 0; j < 2; ++j) {
        int c = w + j * 8;
        int rloc; const unsigned short* s; unsigned short* d;
        if (c < 8) {
            rloc = c * 16 + rl;
            int pa = p0 + rloc; if (pa >= end) pa = end - 1;
            s = h + (size_t)pa * HH;
            d = &A[0][c * 16][0];
        } else {
            rloc = (c - 8) * 16 + rl;
            s = w2p + (size_t)(c0 + rloc) * HH;
            d = &B[0][(c - 8) * 16][0];
        }
        int f = (rloc & 3) ^ ((rloc >> 2) & 3);
        gsrc[j]  = s + (sl ^ f) * 8;
        lbase[j] = d;
    }
    const int bstr = 128 * 32;

    const f4 z4 = {0.f, 0.f, 0.f, 0.f};
    f4 acc[2][4] = {{z4, z4, z4, z4}, {z4, z4, z4, z4}};
    const int sw = (quad ^ (l16 & 3) ^ (l16 >> 2)) * 8;
    const int ra0 = wr * 32 + l16, ra1 = ra0 + 16;
    const int cbase = wc * 64;

    auto STAGE = [&](int buf, int kt) {
        #pragma unroll
        for (int j = 0; j < 2; ++j)
            gld16(gsrc[j] + kt * 32, lbase[j] + buf * bstr);
    };
    auto COMPUTE = [&](int buf) {
        bfrag a0 = *(const bfrag*)&A[buf][ra0][sw];
        bfrag a1 = *(const bfrag*)&A[buf][ra1][sw];
        #pragma unroll
        for (int cb = 0; cb < 4; ++cb) {
            bfrag bb = *(const bfrag*)&B[buf][cbase + cb * 16 + l16][sw];
            acc[0][cb] = MF(a0, bb, acc[0][cb]);
            acc[1][cb] = MF(a1, bb, acc[1][cb]);
        }
    };

    STAGE(0, 0);
    STAGE(1, 1);
    for (int kt = 0; kt < 16; ++kt) {
        if (kt < 15) asm volatile("s_waitcnt vmcnt(2)" ::: "memory");
        else         asm volatile("s_waitcnt vmcnt(0)" ::: "memory");
        __builtin_amdgcn_s_barrier();
        if (kt < 14) STAGE((kt + 2) % 3, kt + 2);
        COMPUTE(kt % 3);
    }

    // bias + v-write + per-row sum(v^2); wave (wr,wc) owns rows p0+wr*32, cols c0+wc*64
    const int pw0 = p0 + wr * 32;
    const int slot = blockIdx.y * 2 + wc;   // 8 blocks x 2 col-halves = 16 psum slots
    float rs0[4] = {0.f, 0.f, 0.f, 0.f}, rs1[4] = {0.f, 0.f, 0.f, 0.f};
    #pragma unroll
    for (int i = 0; i < 4; ++i) {
        int row0i = quad * 4 + i, row1i = 16 + quad * 4 + i;
        int g0 = pw0 + row0i; if (g0 >= end) g0 = end - 1;
        int g1 = pw0 + row1i; if (g1 >= end) g1 = end - 1;
        int gr0 = brows[g0], gr1 = brows[g1];
        #pragma unroll
        for (int cb = 0; cb < 4; ++cb) {
            int col = c0 + cbase + cb * 16 + l16;
            float bias = eb2[e * H + col];
            float v0 = acc[0][cb][i] + bias;
            float v1 = acc[1][cb][i] + bias;
            vout[(size_t)gr0 * H + col] = v0;
            vout[(size_t)gr1 * H + col] = v1;
            rs0[i] += v0 * v0;
            rs1[i] += v1 * v1;
        }
    }
    #pragma unroll
    for (int i = 0; i < 4; ++i) {
        float s0 = rs0[i], s1 = rs1[i];
        #pragma unroll
        for (int off = 8; off; off >>= 1) {
            s0 += __shfl_xor(s0, off, 16);
            s1 += __shfl_xor(s1, off, 16);
        }
        if (l16 == 0) {
            int g0 = pw0 + quad * 4 + i;      if (g0 >= end) g0 = end - 1;
            int g1 = pw0 + 16 + quad * 4 + i; if (g1 >= end) g1 = end - 1;
            psum[(size_t)brows[g0] * 16 + slot] = s0;
            psum[(size_t)brows[g1] * 16 + slot] = s1;
        }
    }
}

// out = v * scale + q ; scale computed inline from psum (one block per row)
__global__ __launch_bounds__(256) void finalize_kernel(
    float* __restrict__ out, const float* __restrict__ q,
    const float* __restrict__ psum, const float* __restrict__ gval)
{
    const int row = blockIdx.x, t = threadIdx.x;
    float s = 0.f;
    #pragma unroll
    for (int j = 0; j < 16; ++j) s += psum[(size_t)row * 16 + j];
    float g = gval[row];
    float sc = g / fmaxf(g * sqrtf(s), 1e-6f);
    size_t i = (size_t)row * 256 + t;
    float4 v = ((const float4*)out)[i];
    float4 qq = ((const float4*)q)[i];
    float4 o;
    o.x = v.x * sc + qq.x;
    o.y = v.y * sc + qq.y;
    o.z = v.z * sc + qq.z;
    o.w = v.w * sc + qq.w;
    ((float4*)out)[i] = o;
}

extern "C" void kernel_launch(void* const* d_in, const int* in_sizes, int n_in,
                              void* d_out, int out_size, void* d_ws, size_t ws_size,
                              hipStream_t stream) {
    const float* q      = (const float*)d_in[0];
    const float* cls1_w = (const float*)d_in[1];
    const float* cls1_b = (const float*)d_in[2];
    const float* cls3_w = (const float*)d_in[3];
    const float* cls3_b = (const float*)d_in[4];
    const float* exp_w1 = (const float*)d_in[5];
    const float* exp_b1 = (const float*)d_in[6];
    const float* exp_w2 = (const float*)d_in[7];
    const float* exp_b2 = (const float*)d_in[8];
    float* out = (float*)d_out;

    // ---- workspace layout (~60 MB), lifetime-based aliasing ----
    char* w = (char*)d_ws;
    float* psum   = (float*)w;              w += (size_t)NB * 16 * 4;
    float* logitsf = (float*)w;             w += (size_t)NB * NEXP * 4;
    float* gvalp  = (float*)w;              w += (size_t)NB * 4;
    int* top1     = (int*)w;                w += (size_t)NB * 4;
    int* brows    = (int*)w;                w += (size_t)NB * 4;
    int* ambig_rows = (int*)w;              w += (size_t)NB * 4;
    int* counts   = (int*)w;                w += 16 * 4;
    int* ambig_cnt = (int*)w;               w += 4 * 4;
    int* tm_e     = (int*)w;                w += NT128 * 4;
    int* tm_p     = (int*)w;                w += NT128 * 4;
    int* tm_end   = (int*)w;                w += NT128 * 4;
    w = (char*)(((size_t)w + 15) & ~(size_t)15);
    unsigned short* qhi  = (unsigned short*)w;  w += (size_t)NB * H * 2;   // lives whole pipeline
    unsigned short* qlo  = (unsigned short*)w;  w += (size_t)NB * H * 2;   // dead after g1 -> ew2b
    char* scratch16 = w;                        w += (size_t)NB * HH * 2 * 2;  // 16MB: x1buf (fixup), then ew1b
    unsigned short* hbuf = (unsigned short*)w;  w += (size_t)NB * HH * 2;
    unsigned short* w1hi = (unsigned short*)w;  w += (size_t)HH * H * 2;
    unsigned short* w1lo = (unsigned short*)w;  w += (size_t)HH * H * 2;
    float* x1buf = (float*)scratch16;              // fixup scratch (fixup1 -> fixup2)
    unsigned short* ew1b = (unsigned short*)scratch16;  // expert w1 bf16 (cvtB -> exp1; cvtB after fixup2)
    unsigned short* ew2b = qlo;                    // expert w2 bf16 (cvtB -> exp2; qlo dead after g1)

    cvtA_kernel<<<8704, 256, 0, stream>>>(q, cls1_w, qhi, qlo, w1hi, w1lo,
                                          logitsf, counts, ambig_cnt);
    g1_kernel<<<dim3(NB / 128, 4), 512, 0, stream>>>(qhi, qlo, w1hi, w1lo, cls1_b,
                                                     cls3_w, logitsf);
    argmax_kernel<<<NB / 256, 256, 0, stream>>>(logitsf, cls3_b, top1, gvalp, counts,
                                                ambig_rows, ambig_cnt);
    fixup1_kernel<<<256, 256, 0, stream>>>(q, cls1_w, cls1_b, ambig_rows, ambig_cnt, x1buf);
    fixup2_kernel<<<64, 256, 0, stream>>>(x1buf, cls3_w, cls3_b, ambig_rows, ambig_cnt,
                                          top1, gvalp, counts);
    cvtB_kernel<<<16384, 256, 0, stream>>>(exp_w1, exp_w2, ew1b, ew2b);
    osc_kernel<<<1, 256, 0, stream>>>(counts, tm_e, tm_p, tm_end, top1, brows);
    exp1_kernel<<<dim3(NT128, 4), 512, 0, stream>>>(qhi, ew1b, exp_b1,
                                                    tm_e, tm_p, tm_end, brows, hbuf);
    exp2_kernel<<<dim3(NT128, 8), 512, 0, stream>>>(hbuf, ew2b, exp_b2,
                                                    tm_e, tm_p, tm_end, brows, out, psum);
    finalize_kernel<<<NB, 256, 0, stream>>>(out, q, psum, gvalp);
}